// Round 4
// baseline (1885.996 us; speedup 1.0000x reference)
//
#include <hip/hip_runtime.h>

#define F     128       // feature width
#define NPB   128       // nodes per bucket
#define NPBS  7         // log2(NPB)
#define CAP   6144      // bucket capacity (mean 2046, +91 sigma)
#define EPA   4         // edges per thread in build (ILP without killing occupancy)
#define BR    64        // rows per fp32-GEMM block tile (fallback)
#define KC    32        // k-chunk (fallback GEMM)

typedef short bf16x8 __attribute__((ext_vector_type(8)));
typedef float f32x4  __attribute__((ext_vector_type(4)));

__device__ __forceinline__ unsigned short f32_to_bf16_rne(float x) {
    unsigned u = __float_as_uint(x);
    u += 0x7fffu + ((u >> 16) & 1u);
    return (unsigned short)(u >> 16);
}

// ---------------------------------------------------------------------------
// Kernel 0: convert h (fp32->bf16) and W (fp32->bf16) in one launch.
// ---------------------------------------------------------------------------
__global__ __launch_bounds__(256) void conv_bf16_kernel(
        const float* __restrict__ h, unsigned short* __restrict__ hb, int n4h,
        const float* __restrict__ Wf, unsigned short* __restrict__ Wb, int n4w) {
    int stride = gridDim.x * blockDim.x;
    int n4 = n4h + n4w;
    for (int i = blockIdx.x * blockDim.x + threadIdx.x; i < n4; i += stride) {
        const float* sp; unsigned short* dp; long j;
        if (i < n4h) { sp = h;  dp = hb; j = i; }
        else         { sp = Wf; dp = Wb; j = i - n4h; }
        float4 v = *(const float4*)(sp + 4 * j);
        ushort4 o;
        o.x = f32_to_bf16_rne(v.x);
        o.y = f32_to_bf16_rne(v.y);
        o.z = f32_to_bf16_rne(v.z);
        o.w = f32_to_bf16_rne(v.w);
        *(ushort4*)(dp + 4 * j) = o;
    }
}

// ---------------------------------------------------------------------------
// Kernel A: append edges into per-bucket pools. bucket = dst>>7.
// Appends to one bucket are temporally dense -> full-line merges in L2
// (vs round-3 [node][pos] slots: 16x partial-line write amplification).
// Entry = (dst&127)<<20 | src  (requires src < 2^20; else fallback tier).
// Overflow (never fires, mean 2046 vs CAP 6144): atomic fp32 h row into out.
// ---------------------------------------------------------------------------
__global__ __launch_bounds__(256) void build_buckets_kernel(
        const int* __restrict__ src,
        const int* __restrict__ dst,
        const float* __restrict__ h,
        int* __restrict__ bcnt,
        int* __restrict__ bpool,
        float* __restrict__ out,
        int n_edges) {
    const int T = gridDim.x * blockDim.x;
    const int t = blockIdx.x * blockDim.x + threadIdx.x;

    for (long g = 0; g < n_edges; g += (long)EPA * T) {
        int  s[EPA], d[EPA], p[EPA];
        bool ok[EPA];
        #pragma unroll
        for (int j = 0; j < EPA; ++j) {
            long idx = g + (long)j * T + t;
            ok[j] = idx < n_edges;
            if (ok[j]) { s[j] = src[idx]; d[j] = dst[idx]; }
        }
        #pragma unroll
        for (int j = 0; j < EPA; ++j)
            if (ok[j]) p[j] = atomicAdd(&bcnt[d[j] >> NPBS], 1);
        #pragma unroll
        for (int j = 0; j < EPA; ++j) {
            if (!ok[j]) continue;
            if (p[j] < CAP) {
                bpool[(long)(d[j] >> NPBS) * CAP + p[j]] =
                    ((d[j] & (NPB - 1)) << 20) | s[j];
            } else {                                  // cold correctness path
                const float* hr = h + (long)s[j] * F;
                float* o = out + (long)d[j] * F;
                for (int k = 0; k < F; ++k) unsafeAtomicAdd(o + k, hr[k]);
            }
        }
    }
}

// ---------------------------------------------------------------------------
// Kernel B: per-bucket aggregate. 128-node x 128-feat fp32 accumulator in
// 64 KB LDS; edges in arbitrary order via ds_add_f32 (2 lanes/bank = free).
// Each lane owns 2 feats of the broadcast h row. Writes out rows once, fp32.
// ---------------------------------------------------------------------------
__global__ __launch_bounds__(256) void bucket_gather_kernel(
        const unsigned short* __restrict__ hb,
        const int* __restrict__ bcnt,
        const int* __restrict__ bpool,
        float* __restrict__ out,
        int n_nodes) {
    __shared__ float agg[NPB * F];                     // 64 KB
    const int b = blockIdx.x;
    const int tid = threadIdx.x;

    for (int i = tid; i < NPB * F; i += 256) agg[i] = 0.f;
    __syncthreads();

    const int total = bcnt[b];
    const int count = min(total, CAP);
    const int* bp = bpool + (long)b * CAP;
    const int lane = tid & 63;
    const int w = tid >> 6;

    // waves take interleaved batches of 8 edges -> 8 row-loads in flight
    for (int base = w * 8; base < count; base += 32) {
        const int lim = min(8, count - base);
        unsigned v[8]; int dl[8];
        #pragma unroll
        for (int j = 0; j < 8; ++j) {
            if (j < lim) {
                int e = bp[base + j];                  // wave-uniform
                dl[j] = e >> 20;
                int s  = e & 0xFFFFF;
                v[j] = *(const unsigned*)(hb + ((long)s << NPBS) + (lane << 1));
            }
        }
        #pragma unroll
        for (int j = 0; j < 8; ++j) {
            if (j < lim) {
                float x = __uint_as_float(v[j] << 16);
                float y = __uint_as_float(v[j] & 0xffff0000u);
                float* ap = &agg[(dl[j] << NPBS) + (lane << 1)];
                atomicAdd(ap, x);                      // ds_add_f32, no return
                atomicAdd(ap + 1, y);
            }
        }
    }
    __syncthreads();

    // epilogue: LDS -> out (fp32), merging overflow contributions
    const bool ovf = total > CAP;
    const int nb0 = b << NPBS;
    for (int i = tid; i < NPB * (F / 4); i += 256) {
        int n = nb0 + (i >> 5);
        if (n >= n_nodes) break;                       // i>>5 monotone in i
        float4 vv = *(const float4*)&agg[i << 2];
        float* op = out + ((long)n << NPBS) + ((i & 31) << 2);
        if (ovf) {
            float4 p = *(const float4*)op;
            vv.x += p.x; vv.y += p.y; vv.z += p.z; vv.w += p.w;
        }
        *(float4*)op = vv;
    }
}

// ---------------------------------------------------------------------------
// Kernel C: out = relu(agg @ W.T + b) via MFMA bf16, IN PLACE on d_out.
// One wave per 16 rows; A frags cvt'd fp32->bf16 in-register from out rows;
// B frags are 16B loads from bf16 W (L2-resident broadcast). No LDS.
// Layouts (measured, m89/m91/m120): A[m=lane&15][k=quad*8+j],
// B[n=lane&15][k=quad*8+j], C: col=lane&15, row=quad*4+reg.
// ---------------------------------------------------------------------------
__global__ __launch_bounds__(256) void gemm_mfma_kernel(
        float* __restrict__ out,                      // in: agg fp32, out: result
        const unsigned short* __restrict__ Wb,        // [128][128] bf16
        const float* __restrict__ bias,
        int n_rows) {
    const int wave = (blockIdx.x * 256 + threadIdx.x) >> 6;
    const int lane = threadIdx.x & 63;
    const int m0 = wave * 16;
    if (m0 >= n_rows) return;
    const int mn   = lane & 15;                       // A row / B col offset
    const int quad = lane >> 4;

    const int rowc = min(m0 + mn, n_rows - 1);        // clamp tail reads
    const float* arow = out + (long)rowc * F + quad * 8;

    // load + convert all 4 A fragments BEFORE any stores (in-place safety)
    bf16x8 afr[4];
    #pragma unroll
    for (int kk = 0; kk < 4; ++kk) {
        float4 p0 = *(const float4*)(arow + kk * 32);
        float4 p1 = *(const float4*)(arow + kk * 32 + 4);
        bf16x8 f;
        f[0] = (short)f32_to_bf16_rne(p0.x);
        f[1] = (short)f32_to_bf16_rne(p0.y);
        f[2] = (short)f32_to_bf16_rne(p0.z);
        f[3] = (short)f32_to_bf16_rne(p0.w);
        f[4] = (short)f32_to_bf16_rne(p1.x);
        f[5] = (short)f32_to_bf16_rne(p1.y);
        f[6] = (short)f32_to_bf16_rne(p1.z);
        f[7] = (short)f32_to_bf16_rne(p1.w);
        afr[kk] = f;
    }

    f32x4 acc[8];
    #pragma unroll
    for (int t = 0; t < 8; ++t) acc[t] = (f32x4){0.f, 0.f, 0.f, 0.f};

    #pragma unroll
    for (int kk = 0; kk < 4; ++kk) {
        #pragma unroll
        for (int t = 0; t < 8; ++t) {
            const unsigned short* wp = Wb + (long)(t * 16 + mn) * F + kk * 32 + quad * 8;
            bf16x8 bfr = *(const bf16x8*)wp;          // 16B load
            acc[t] = __builtin_amdgcn_mfma_f32_16x16x32_bf16(afr[kk], bfr, acc[t], 0, 0, 0);
        }
    }

    #pragma unroll
    for (int t = 0; t < 8; ++t) {
        const int col = t * 16 + mn;
        const float bv = bias[col];
        #pragma unroll
        for (int r = 0; r < 4; ++r) {
            const int orow = m0 + quad * 4 + r;
            if (orow < n_rows) {
                float v = acc[t][r] + bv;
                out[(long)orow * F + col] = v > 0.f ? v : 0.f;
            }
        }
    }
}

// ---------------------------------------------------------------------------
// Fallback tier (tiny ws or huge node ids): direct atomic scatter + fp32 GEMM.
// ---------------------------------------------------------------------------
__global__ void scatter_add_kernel(const float* __restrict__ h,
                                   const int* __restrict__ src,
                                   const int* __restrict__ dst,
                                   float* __restrict__ agg,
                                   long total) {
    long stride = (long)gridDim.x * blockDim.x;
    for (long i = (long)blockIdx.x * blockDim.x + threadIdx.x; i < total; i += stride) {
        int e    = (int)(i >> 5);
        int lane = (int)(i & 31);
        int s = src[e];
        int d = dst[e];
        float4 v = *(const float4*)(h + (long)s * F + (lane << 2));
        float* o = agg + (long)d * F + (lane << 2);
        unsafeAtomicAdd(o + 0, v.x);
        unsafeAtomicAdd(o + 1, v.y);
        unsafeAtomicAdd(o + 2, v.z);
        unsafeAtomicAdd(o + 3, v.w);
    }
}

__global__ __launch_bounds__(256) void gemm_bias_relu_inplace(
        float* __restrict__ out,
        const float* __restrict__ W,
        const float* __restrict__ bias,
        int n_rows) {
    __shared__ __align__(16) float a_t[KC][BR + 4];
    __shared__ __align__(16) float w_t[KC][F + 4];
    const int tid = threadIdx.x;
    const int tx = tid & 15;
    const int ty = tid >> 4;
    const int row0 = blockIdx.x * BR;
    float acc[4][8];
    #pragma unroll
    for (int i = 0; i < 4; ++i)
        #pragma unroll
        for (int j = 0; j < 8; ++j) acc[i][j] = 0.f;
    for (int kc = 0; kc < F; kc += KC) {
        #pragma unroll
        for (int p = 0; p < 2; ++p) {
            int q = tid + p * 256, r = q >> 3, kq = q & 7;
            int row = row0 + r;
            float4 v = make_float4(0.f, 0.f, 0.f, 0.f);
            if (row < n_rows) v = *(const float4*)(out + (long)row * F + kc + (kq << 2));
            a_t[kq * 4 + 0][r] = v.x; a_t[kq * 4 + 1][r] = v.y;
            a_t[kq * 4 + 2][r] = v.z; a_t[kq * 4 + 3][r] = v.w;
        }
        #pragma unroll
        for (int p = 0; p < 4; ++p) {
            int q = tid + p * 256, j = q >> 3, kq = q & 7;
            float4 v = *(const float4*)(W + (long)j * F + kc + (kq << 2));
            w_t[kq * 4 + 0][j] = v.x; w_t[kq * 4 + 1][j] = v.y;
            w_t[kq * 4 + 2][j] = v.z; w_t[kq * 4 + 3][j] = v.w;
        }
        __syncthreads();
        #pragma unroll
        for (int k = 0; k < KC; ++k) {
            float4 av = *(const float4*)&a_t[k][ty << 2];
            float4 w0 = *(const float4*)&w_t[k][tx << 2];
            float4 w1 = *(const float4*)&w_t[k][64 + (tx << 2)];
            float a4[4] = {av.x, av.y, av.z, av.w};
            float wv[8] = {w0.x, w0.y, w0.z, w0.w, w1.x, w1.y, w1.z, w1.w};
            #pragma unroll
            for (int i = 0; i < 4; ++i)
                #pragma unroll
                for (int j = 0; j < 8; ++j) acc[i][j] += a4[i] * wv[j];
        }
        __syncthreads();
    }
    float4 b0 = *(const float4*)(bias + (tx << 2));
    float4 b1 = *(const float4*)(bias + 64 + (tx << 2));
    #pragma unroll
    for (int i = 0; i < 4; ++i) {
        int row = row0 + (ty << 2) + i;
        if (row < n_rows) {
            float4 r0, r1;
            r0.x = fmaxf(acc[i][0] + b0.x, 0.f); r0.y = fmaxf(acc[i][1] + b0.y, 0.f);
            r0.z = fmaxf(acc[i][2] + b0.z, 0.f); r0.w = fmaxf(acc[i][3] + b0.w, 0.f);
            r1.x = fmaxf(acc[i][4] + b1.x, 0.f); r1.y = fmaxf(acc[i][5] + b1.y, 0.f);
            r1.z = fmaxf(acc[i][6] + b1.z, 0.f); r1.w = fmaxf(acc[i][7] + b1.w, 0.f);
            *(float4*)(out + (long)row * F + (tx << 2)) = r0;
            *(float4*)(out + (long)row * F + 64 + (tx << 2)) = r1;
        }
    }
}

extern "C" void kernel_launch(void* const* d_in, const int* in_sizes, int n_in,
                              void* d_out, int out_size, void* d_ws, size_t ws_size,
                              hipStream_t stream) {
    const float* h   = (const float*)d_in[0];
    const int*   src = (const int*)d_in[1];
    const int*   dst = (const int*)d_in[2];
    const float* W   = (const float*)d_in[3];
    const float* b   = (const float*)d_in[4];
    float* out = (float*)d_out;

    const int n_nodes = in_sizes[0] / F;
    const int n_edges = in_sizes[1];
    const int NB = (n_nodes + NPB - 1) >> NPBS;

    // ws layout: bcnt | bpool | hb | Wb
    const size_t off_bcnt  = 0;
    const size_t off_bpool = 4096;
    const size_t off_hb    = off_bpool + (size_t)NB * CAP * sizeof(int);
    const size_t off_wb    = off_hb + (size_t)n_nodes * F * sizeof(unsigned short);
    const size_t need      = off_wb + (size_t)F * F * sizeof(unsigned short);

    if (ws_size >= need && n_nodes < (1 << 20) && (size_t)NB * sizeof(int) <= 4096) {
        int* bcnt  = (int*)((char*)d_ws + off_bcnt);
        int* bpool = (int*)((char*)d_ws + off_bpool);
        unsigned short* hb = (unsigned short*)((char*)d_ws + off_hb);
        unsigned short* Wb = (unsigned short*)((char*)d_ws + off_wb);

        hipMemsetAsync(bcnt, 0, (size_t)NB * sizeof(int), stream);
        hipMemsetAsync(out, 0, (size_t)out_size * sizeof(float), stream);  // overflow path

        const int n4h = n_nodes * (F / 4);
        const int n4w = F * F / 4;
        conv_bf16_kernel<<<2048, 256, 0, stream>>>(h, hb, n4h, W, Wb, n4w);

        const int bgrid = (n_edges + 256 * EPA - 1) / (256 * EPA);
        build_buckets_kernel<<<bgrid, 256, 0, stream>>>(
            src, dst, h, bcnt, bpool, out, n_edges);

        bucket_gather_kernel<<<NB, 256, 0, stream>>>(hb, bcnt, bpool, out, n_nodes);

        const int ggrid = (n_nodes + 63) / 64;        // 4 waves x 16 rows
        gemm_mfma_kernel<<<ggrid, 256, 0, stream>>>(out, Wb, b, n_nodes);
    } else {
        hipMemsetAsync(out, 0, (size_t)out_size * sizeof(float), stream);
        scatter_add_kernel<<<16384, 256, 0, stream>>>(
            h, src, dst, out, (long)n_edges * 32);
        const int gblocks = (n_nodes + BR - 1) / BR;
        gemm_bias_relu_inplace<<<gblocks, 256, 0, stream>>>(out, W, b, n_nodes);
    }
}

// Round 5
// 304.193 us; speedup vs baseline: 6.2000x; 6.2000x over previous
//
#include <hip/hip_runtime.h>

#define F     128       // feature width
#define NPB   128       // nodes per bucket
#define NPBS  7         // log2(NPB)
#define CAP   6144      // bucket capacity (mean 2046, +90 sigma)
#define NBMAX 1024      // max buckets handled by fast tier
#define BR    64        // rows per fp32-GEMM block tile (fallback)
#define KC    32        // k-chunk (fallback GEMM)

typedef short bf16x8 __attribute__((ext_vector_type(8)));
typedef float f32x4  __attribute__((ext_vector_type(4)));

__device__ __forceinline__ unsigned short f32_to_bf16_rne(float x) {
    unsigned u = __float_as_uint(x);
    u += 0x7fffu + ((u >> 16) & 1u);
    return (unsigned short)(u >> 16);
}

// ---------------------------------------------------------------------------
// Kernel 0: convert h (fp32->bf16) and W (fp32->bf16) in one launch.
// ---------------------------------------------------------------------------
__global__ __launch_bounds__(256) void conv_bf16_kernel(
        const float* __restrict__ h, unsigned short* __restrict__ hb, int n4h,
        const float* __restrict__ Wf, unsigned short* __restrict__ Wb, int n4w) {
    int stride = gridDim.x * blockDim.x;
    int n4 = n4h + n4w;
    for (int i = blockIdx.x * blockDim.x + threadIdx.x; i < n4; i += stride) {
        const float* sp; unsigned short* dp; long j;
        if (i < n4h) { sp = h;  dp = hb; j = i; }
        else         { sp = Wf; dp = Wb; j = i - n4h; }
        float4 v = *(const float4*)(sp + 4 * j);
        ushort4 o;
        o.x = f32_to_bf16_rne(v.x);
        o.y = f32_to_bf16_rne(v.y);
        o.z = f32_to_bf16_rne(v.z);
        o.w = f32_to_bf16_rne(v.w);
        *(ushort4*)(dp + 4 * j) = o;
    }
}

// ---------------------------------------------------------------------------
// Kernel A: two-pass block-radix bucket build.
// Each block owns a contiguous edge range: (1) LDS int histogram of buckets
// (native ds_add, no fp atomics), (2) ONE global rtn-atomic per (block,bucket)
// reserves a dense range in the pool (~512 atomics/counter instead of
// round-3/4's 1.6M same-line atomics), (3) scatter entries into the reserved
// run -> dense, line-merged writes. Entry = (dst&127)<<20 | src.
// Overflow (never for this dataset): fp32 atomic h row into pre-zeroed out.
// ---------------------------------------------------------------------------
__global__ __launch_bounds__(256) void build_buckets_kernel(
        const int* __restrict__ src,
        const int* __restrict__ dst,
        const float* __restrict__ h,
        int* __restrict__ bcnt,
        int* __restrict__ bpool,
        float* __restrict__ out,
        int n_edges, int NB) {
    __shared__ int hist[NBMAX];     // pass1: counts; pass3: cursor
    __shared__ int basep[NBMAX];    // reserved global base per bucket

    const int per = (n_edges + gridDim.x - 1) / gridDim.x;
    const int lo = blockIdx.x * per;
    const int hi = min(n_edges, lo + per);
    const int tid = threadIdx.x;

    for (int i = tid; i < NB; i += 256) hist[i] = 0;
    __syncthreads();

    for (int i = lo + tid; i < hi; i += 256)
        atomicAdd(&hist[dst[i] >> NPBS], 1);            // ds_add_u32, native
    __syncthreads();

    for (int i = tid; i < NB; i += 256) {
        int c = hist[i];
        basep[i] = c ? atomicAdd(&bcnt[i], c) : 0;      // range reservation
        hist[i] = 0;                                    // reuse as cursor
    }
    __syncthreads();

    for (int i = lo + tid; i < hi; i += 256) {
        int d = dst[i], s = src[i];
        int bk = d >> NPBS;
        int p = atomicAdd(&hist[bk], 1);                // ds_add_rtn_u32
        long idx = (long)basep[bk] + p;
        if (idx < CAP) {
            bpool[(long)bk * CAP + idx] = ((d & (NPB - 1)) << 20) | s;
        } else {                                        // cold correctness path
            const float* hr = h + (long)s * F;
            float* o = out + (long)d * F;
            for (int k = 0; k < F; ++k) unsafeAtomicAdd(o + k, hr[k]);
        }
    }
}

// ---------------------------------------------------------------------------
// Kernel B: per-bucket aggregate, NO fp atomics (round-4's atomicAdd(float*)
// on LDS compiled to a CAS loop -> 1360us).  Plan:
//   phase 1: CSR-ify the bucket in LDS: histogram 128 node degrees (int
//            atomics), wave-0 shfl prefix scan, scatter edge ids sorted.
//   phase 2: each wave owns 32 nodes; accumulates h rows in REGISTERS
//            (lane = 2 feats), 8 loads in flight via predicated batching;
//            one fp32 float2 store per row.
// LDS = 24KB elist + 1.5KB -> 6 blocks/CU.
// ---------------------------------------------------------------------------
__global__ __launch_bounds__(256) void bucket_gather_kernel(
        const unsigned short* __restrict__ hb,
        const int* __restrict__ bcnt,
        const int* __restrict__ bpool,
        float* __restrict__ out,
        int n_nodes) {
    __shared__ int ecnt[NPB];
    __shared__ int eofs[NPB];
    __shared__ int epos[NPB];
    __shared__ int elist[CAP];

    const int b = blockIdx.x;
    const int tid = threadIdx.x;
    const int total = bcnt[b];
    const int count = min(total, CAP);
    const int* bp = bpool + (long)b * CAP;

    if (tid < NPB) ecnt[tid] = 0;
    __syncthreads();

    // --- histogram node degrees (native int LDS atomics) ---
    for (int i = tid; i < count; i += 256)
        atomicAdd(&ecnt[bp[i] >> 20], 1);
    __syncthreads();

    // --- exclusive prefix scan of 128 degrees (wave 0, shfl) ---
    if (tid < 64) {
        int a0 = ecnt[tid];
        int a1 = ecnt[64 + tid];
        int s0 = a0, s1 = a1;
        #pragma unroll
        for (int d = 1; d < 64; d <<= 1) {
            int t0 = __shfl_up(s0, d);
            int t1 = __shfl_up(s1, d);
            if (tid >= d) { s0 += t0; s1 += t1; }
        }
        int tot0 = __shfl(s0, 63);
        eofs[tid]      = s0 - a0;
        eofs[64 + tid] = tot0 + s1 - a1;
        epos[tid]      = s0 - a0;
        epos[64 + tid] = tot0 + s1 - a1;
    }
    __syncthreads();

    // --- scatter edge ids into per-node segments ---
    for (int i = tid; i < count; i += 256) {
        int e = bp[i];
        int n = e >> 20;
        int p = atomicAdd(&epos[n], 1);                 // ds_add_rtn_u32
        elist[p] = e & 0xFFFFF;
    }
    __syncthreads();

    // --- phase 2: register accumulation, one wave per node group ---
    const int lane = tid & 63;
    const int w = tid >> 6;
    const bool ovf = total > CAP;

    for (int nl = w; nl < NPB; nl += 4) {
        int n = (b << NPBS) + nl;
        if (n >= n_nodes) break;
        const int deg = ecnt[nl];
        const int off = eofs[nl];

        float ax = 0.f, ay = 0.f;
        for (int i = 0; i < deg; i += 8) {              // 8 loads in flight
            unsigned v[8]; bool val[8];
            #pragma unroll
            for (int j = 0; j < 8; ++j) {
                val[j] = (i + j) < deg;
                int sid = elist[off + (val[j] ? i + j : 0)];   // uniform -> bcast
                v[j] = *(const unsigned*)(hb + ((long)sid << NPBS) + (lane << 1));
            }
            #pragma unroll
            for (int j = 0; j < 8; ++j) {
                if (val[j]) {
                    ax += __uint_as_float(v[j] << 16);
                    ay += __uint_as_float(v[j] & 0xffff0000u);
                }
            }
        }

        float* o = out + ((long)n << NPBS) + (lane << 1);
        if (ovf) { float2 p = *(const float2*)o; ax += p.x; ay += p.y; }
        *(float2*)o = make_float2(ax, ay);
    }
}

// ---------------------------------------------------------------------------
// Kernel C: out = relu(agg @ W.T + b) via MFMA bf16, IN PLACE on d_out.
// (unchanged from round 4 — verified correct)
// ---------------------------------------------------------------------------
__global__ __launch_bounds__(256) void gemm_mfma_kernel(
        float* __restrict__ out,
        const unsigned short* __restrict__ Wb,
        const float* __restrict__ bias,
        int n_rows) {
    const int wave = (blockIdx.x * 256 + threadIdx.x) >> 6;
    const int lane = threadIdx.x & 63;
    const int m0 = wave * 16;
    if (m0 >= n_rows) return;
    const int mn   = lane & 15;
    const int quad = lane >> 4;

    const int rowc = min(m0 + mn, n_rows - 1);
    const float* arow = out + (long)rowc * F + quad * 8;

    bf16x8 afr[4];
    #pragma unroll
    for (int kk = 0; kk < 4; ++kk) {
        float4 p0 = *(const float4*)(arow + kk * 32);
        float4 p1 = *(const float4*)(arow + kk * 32 + 4);
        bf16x8 f;
        f[0] = (short)f32_to_bf16_rne(p0.x);
        f[1] = (short)f32_to_bf16_rne(p0.y);
        f[2] = (short)f32_to_bf16_rne(p0.z);
        f[3] = (short)f32_to_bf16_rne(p0.w);
        f[4] = (short)f32_to_bf16_rne(p1.x);
        f[5] = (short)f32_to_bf16_rne(p1.y);
        f[6] = (short)f32_to_bf16_rne(p1.z);
        f[7] = (short)f32_to_bf16_rne(p1.w);
        afr[kk] = f;
    }

    f32x4 acc[8];
    #pragma unroll
    for (int t = 0; t < 8; ++t) acc[t] = (f32x4){0.f, 0.f, 0.f, 0.f};

    #pragma unroll
    for (int kk = 0; kk < 4; ++kk) {
        #pragma unroll
        for (int t = 0; t < 8; ++t) {
            const unsigned short* wp = Wb + (long)(t * 16 + mn) * F + kk * 32 + quad * 8;
            bf16x8 bfr = *(const bf16x8*)wp;
            acc[t] = __builtin_amdgcn_mfma_f32_16x16x32_bf16(afr[kk], bfr, acc[t], 0, 0, 0);
        }
    }

    #pragma unroll
    for (int t = 0; t < 8; ++t) {
        const int col = t * 16 + mn;
        const float bv = bias[col];
        #pragma unroll
        for (int r = 0; r < 4; ++r) {
            const int orow = m0 + quad * 4 + r;
            if (orow < n_rows) {
                float v = acc[t][r] + bv;
                out[(long)orow * F + col] = v > 0.f ? v : 0.f;
            }
        }
    }
}

// ---------------------------------------------------------------------------
// Fallback tier (tiny ws or huge node ids): direct atomic scatter + fp32 GEMM.
// ---------------------------------------------------------------------------
__global__ void scatter_add_kernel(const float* __restrict__ h,
                                   const int* __restrict__ src,
                                   const int* __restrict__ dst,
                                   float* __restrict__ agg,
                                   long total) {
    long stride = (long)gridDim.x * blockDim.x;
    for (long i = (long)blockIdx.x * blockDim.x + threadIdx.x; i < total; i += stride) {
        int e    = (int)(i >> 5);
        int lane = (int)(i & 31);
        int s = src[e];
        int d = dst[e];
        float4 v = *(const float4*)(h + (long)s * F + (lane << 2));
        float* o = agg + (long)d * F + (lane << 2);
        unsafeAtomicAdd(o + 0, v.x);
        unsafeAtomicAdd(o + 1, v.y);
        unsafeAtomicAdd(o + 2, v.z);
        unsafeAtomicAdd(o + 3, v.w);
    }
}

__global__ __launch_bounds__(256) void gemm_bias_relu_inplace(
        float* __restrict__ out,
        const float* __restrict__ W,
        const float* __restrict__ bias,
        int n_rows) {
    __shared__ __align__(16) float a_t[KC][BR + 4];
    __shared__ __align__(16) float w_t[KC][F + 4];
    const int tid = threadIdx.x;
    const int tx = tid & 15;
    const int ty = tid >> 4;
    const int row0 = blockIdx.x * BR;
    float acc[4][8];
    #pragma unroll
    for (int i = 0; i < 4; ++i)
        #pragma unroll
        for (int j = 0; j < 8; ++j) acc[i][j] = 0.f;
    for (int kc = 0; kc < F; kc += KC) {
        #pragma unroll
        for (int p = 0; p < 2; ++p) {
            int q = tid + p * 256, r = q >> 3, kq = q & 7;
            int row = row0 + r;
            float4 v = make_float4(0.f, 0.f, 0.f, 0.f);
            if (row < n_rows) v = *(const float4*)(out + (long)row * F + kc + (kq << 2));
            a_t[kq * 4 + 0][r] = v.x; a_t[kq * 4 + 1][r] = v.y;
            a_t[kq * 4 + 2][r] = v.z; a_t[kq * 4 + 3][r] = v.w;
        }
        #pragma unroll
        for (int p = 0; p < 4; ++p) {
            int q = tid + p * 256, j = q >> 3, kq = q & 7;
            float4 v = *(const float4*)(W + (long)j * F + kc + (kq << 2));
            w_t[kq * 4 + 0][j] = v.x; w_t[kq * 4 + 1][j] = v.y;
            w_t[kq * 4 + 2][j] = v.z; w_t[kq * 4 + 3][j] = v.w;
        }
        __syncthreads();
        #pragma unroll
        for (int k = 0; k < KC; ++k) {
            float4 av = *(const float4*)&a_t[k][ty << 2];
            float4 w0 = *(const float4*)&w_t[k][tx << 2];
            float4 w1 = *(const float4*)&w_t[k][64 + (tx << 2)];
            float a4[4] = {av.x, av.y, av.z, av.w};
            float wv[8] = {w0.x, w0.y, w0.z, w0.w, w1.x, w1.y, w1.z, w1.w};
            #pragma unroll
            for (int i = 0; i < 4; ++i)
                #pragma unroll
                for (int j = 0; j < 8; ++j) acc[i][j] += a4[i] * wv[j];
        }
        __syncthreads();
    }
    float4 b0 = *(const float4*)(bias + (tx << 2));
    float4 b1 = *(const float4*)(bias + 64 + (tx << 2));
    #pragma unroll
    for (int i = 0; i < 4; ++i) {
        int row = row0 + (ty << 2) + i;
        if (row < n_rows) {
            float4 r0, r1;
            r0.x = fmaxf(acc[i][0] + b0.x, 0.f); r0.y = fmaxf(acc[i][1] + b0.y, 0.f);
            r0.z = fmaxf(acc[i][2] + b0.z, 0.f); r0.w = fmaxf(acc[i][3] + b0.w, 0.f);
            r1.x = fmaxf(acc[i][4] + b1.x, 0.f); r1.y = fmaxf(acc[i][5] + b1.y, 0.f);
            r1.z = fmaxf(acc[i][6] + b1.z, 0.f); r1.w = fmaxf(acc[i][7] + b1.w, 0.f);
            *(float4*)(out + (long)row * F + (tx << 2)) = r0;
            *(float4*)(out + (long)row * F + 64 + (tx << 2)) = r1;
        }
    }
}

extern "C" void kernel_launch(void* const* d_in, const int* in_sizes, int n_in,
                              void* d_out, int out_size, void* d_ws, size_t ws_size,
                              hipStream_t stream) {
    const float* h   = (const float*)d_in[0];
    const int*   src = (const int*)d_in[1];
    const int*   dst = (const int*)d_in[2];
    const float* W   = (const float*)d_in[3];
    const float* b   = (const float*)d_in[4];
    float* out = (float*)d_out;

    const int n_nodes = in_sizes[0] / F;
    const int n_edges = in_sizes[1];
    const int NB = (n_nodes + NPB - 1) >> NPBS;

    // ws layout: bcnt | bpool | hb | Wb
    const size_t off_bcnt  = 0;
    const size_t off_bpool = 4096;
    const size_t off_hb    = off_bpool + (size_t)NB * CAP * sizeof(int);
    const size_t off_wb    = off_hb + (size_t)n_nodes * F * sizeof(unsigned short);
    const size_t need      = off_wb + (size_t)F * F * sizeof(unsigned short);

    if (ws_size >= need && n_nodes < (1 << 20) && NB <= NBMAX) {
        int* bcnt  = (int*)((char*)d_ws + off_bcnt);
        int* bpool = (int*)((char*)d_ws + off_bpool);
        unsigned short* hb = (unsigned short*)((char*)d_ws + off_hb);
        unsigned short* Wb = (unsigned short*)((char*)d_ws + off_wb);

        hipMemsetAsync(bcnt, 0, (size_t)NB * sizeof(int), stream);
        hipMemsetAsync(out, 0, (size_t)out_size * sizeof(float), stream);  // overflow path

        const int n4h = n_nodes * (F / 4);
        const int n4w = F * F / 4;
        conv_bf16_kernel<<<2048, 256, 0, stream>>>(h, hb, n4h, W, Wb, n4w);

        build_buckets_kernel<<<512, 256, 0, stream>>>(
            src, dst, h, bcnt, bpool, out, n_edges, NB);

        bucket_gather_kernel<<<NB, 256, 0, stream>>>(hb, bcnt, bpool, out, n_nodes);

        const int ggrid = (n_nodes + 63) / 64;        // 4 waves x 16 rows
        gemm_mfma_kernel<<<ggrid, 256, 0, stream>>>(out, Wb, b, n_nodes);
    } else {
        hipMemsetAsync(out, 0, (size_t)out_size * sizeof(float), stream);
        scatter_add_kernel<<<16384, 256, 0, stream>>>(
            h, src, dst, out, (long)n_edges * 32);
        const int gblocks = (n_nodes + BR - 1) / BR;
        gemm_bias_relu_inplace<<<gblocks, 256, 0, stream>>>(out, W, b, n_nodes);
    }
}

// Round 6
// 263.750 us; speedup vs baseline: 7.1507x; 1.1533x over previous
//
#include <hip/hip_runtime.h>

#define F     128       // feature width
#define NPB   128       // nodes per bucket
#define NPBS  7         // log2(NPB)
#define CAP   6144      // bucket capacity (mean 2046, +90 sigma)
#define NBMAX 1024      // max buckets handled by fast tier
#define SPLIT 4         // gather blocks per bucket
#define NPG   32        // nodes per gather block (NPB/SPLIT)
#define ECAP  1024      // per-gather-block edge list capacity (mean 512, +22 sigma)
#define BR    64        // rows per fp32-GEMM block tile (fallback)
#define KC    32        // k-chunk (fallback GEMM)

typedef short bf16x8 __attribute__((ext_vector_type(8)));
typedef float f32x4  __attribute__((ext_vector_type(4)));

__device__ __forceinline__ unsigned short f32_to_bf16_rne(float x) {
    unsigned u = __float_as_uint(x);
    u += 0x7fffu + ((u >> 16) & 1u);
    return (unsigned short)(u >> 16);
}
__device__ __forceinline__ float bf16_to_f32(unsigned short u) {
    return __uint_as_float((unsigned)u << 16);
}

// ---------------------------------------------------------------------------
// Kernel 0: convert W fp32 -> bf16 (64 KB only; h conversion is now fused
// into the MFMA GEMM that produces h').
// ---------------------------------------------------------------------------
__global__ __launch_bounds__(256) void conv_w_kernel(
        const float* __restrict__ Wf, unsigned short* __restrict__ Wb, int n4) {
    int i = blockIdx.x * blockDim.x + threadIdx.x;
    if (i < n4) {
        float4 v = *(const float4*)(Wf + 4 * (long)i);
        ushort4 o;
        o.x = f32_to_bf16_rne(v.x);
        o.y = f32_to_bf16_rne(v.y);
        o.z = f32_to_bf16_rne(v.z);
        o.w = f32_to_bf16_rne(v.w);
        *(ushort4*)(Wb + 4 * (long)i) = o;
    }
}

// ---------------------------------------------------------------------------
// Kernel 1: h' = h @ W^T via MFMA bf16, h fp32 in, h' bf16 out.
// Algebraic reorder: segment_sum(h[src]) @ W^T == segment_sum((h@W^T)[src]),
// so the GEMM runs on h BEFORE aggregation; gather then fuses bias+relu.
// One wave per 16 rows; A cvt'd fp32->bf16 in-register; B = bf16 W rows
// (L2-resident). C layout (measured m89/m91): col=lane&15, row=quad*4+reg.
// ---------------------------------------------------------------------------
__global__ __launch_bounds__(256) void gemm_h_kernel(
        const float* __restrict__ h,
        const unsigned short* __restrict__ Wb,
        unsigned short* __restrict__ hp,          // [n][128] bf16 out
        int n_rows) {
    const int wave = (blockIdx.x * 256 + threadIdx.x) >> 6;
    const int lane = threadIdx.x & 63;
    const int m0 = wave * 16;
    if (m0 >= n_rows) return;
    const int mn   = lane & 15;
    const int quad = lane >> 4;

    const int rowc = min(m0 + mn, n_rows - 1);
    const float* arow = h + (long)rowc * F + quad * 8;

    bf16x8 afr[4];
    #pragma unroll
    for (int kk = 0; kk < 4; ++kk) {
        float4 p0 = *(const float4*)(arow + kk * 32);
        float4 p1 = *(const float4*)(arow + kk * 32 + 4);
        bf16x8 f;
        f[0] = (short)f32_to_bf16_rne(p0.x);
        f[1] = (short)f32_to_bf16_rne(p0.y);
        f[2] = (short)f32_to_bf16_rne(p0.z);
        f[3] = (short)f32_to_bf16_rne(p0.w);
        f[4] = (short)f32_to_bf16_rne(p1.x);
        f[5] = (short)f32_to_bf16_rne(p1.y);
        f[6] = (short)f32_to_bf16_rne(p1.z);
        f[7] = (short)f32_to_bf16_rne(p1.w);
        afr[kk] = f;
    }

    f32x4 acc[8];
    #pragma unroll
    for (int t = 0; t < 8; ++t) acc[t] = (f32x4){0.f, 0.f, 0.f, 0.f};

    #pragma unroll
    for (int kk = 0; kk < 4; ++kk) {
        #pragma unroll
        for (int t = 0; t < 8; ++t) {
            const unsigned short* wp = Wb + (long)(t * 16 + mn) * F + kk * 32 + quad * 8;
            bf16x8 bfr = *(const bf16x8*)wp;
            acc[t] = __builtin_amdgcn_mfma_f32_16x16x32_bf16(afr[kk], bfr, acc[t], 0, 0, 0);
        }
    }

    #pragma unroll
    for (int t = 0; t < 8; ++t) {
        const int col = t * 16 + mn;
        #pragma unroll
        for (int r = 0; r < 4; ++r) {
            const int orow = m0 + quad * 4 + r;
            if (orow < n_rows)
                hp[(long)orow * F + col] = f32_to_bf16_rne(acc[t][r]);
        }
    }
}

// ---------------------------------------------------------------------------
// Kernel A: two-pass block-radix bucket build (unchanged structure).
// Overflow path (never fires: CAP=+90sigma) adds h' row into pre-zeroed out.
// ---------------------------------------------------------------------------
__global__ __launch_bounds__(256) void build_buckets_kernel(
        const int* __restrict__ src,
        const int* __restrict__ dst,
        const unsigned short* __restrict__ hp,
        int* __restrict__ bcnt,
        int* __restrict__ bpool,
        float* __restrict__ out,
        int n_edges, int NB) {
    __shared__ int hist[NBMAX];
    __shared__ int basep[NBMAX];

    const int per = (n_edges + gridDim.x - 1) / gridDim.x;
    const int lo = blockIdx.x * per;
    const int hi = min(n_edges, lo + per);
    const int tid = threadIdx.x;

    for (int i = tid; i < NB; i += 256) hist[i] = 0;
    __syncthreads();

    for (int i = lo + tid; i < hi; i += 256)
        atomicAdd(&hist[dst[i] >> NPBS], 1);
    __syncthreads();

    for (int i = tid; i < NB; i += 256) {
        int c = hist[i];
        basep[i] = c ? atomicAdd(&bcnt[i], c) : 0;
        hist[i] = 0;
    }
    __syncthreads();

    for (int i = lo + tid; i < hi; i += 256) {
        int d = dst[i], s = src[i];
        int bk = d >> NPBS;
        int p = atomicAdd(&hist[bk], 1);
        long idx = (long)basep[bk] + p;
        if (idx < CAP) {
            bpool[(long)bk * CAP + idx] = ((d & (NPB - 1)) << 20) | s;
        } else {                                        // cold correctness path
            float* o = out + (long)d * F;
            const unsigned short* hr = hp + (long)s * F;
            for (int k = 0; k < F; ++k) unsafeAtomicAdd(o + k, bf16_to_f32(hr[k]));
        }
    }
}

// ---------------------------------------------------------------------------
// Kernel B: gather-aggregate + bias + relu fused.  One block per
// (bucket, 32-node quarter): grid = NB*4 (round-5's 782 blocks -> 28%
// occupancy was the gather wall). Filters bucket pool for its node range,
// builds mini-CSR in 4.5 KB LDS (int atomics + 32-wide shfl scan), then
// register accumulation (lane = 2 feats, 8 loads in flight), epilogue
// applies bias+relu and writes each out row exactly once.
// ---------------------------------------------------------------------------
__global__ __launch_bounds__(256) void bucket_gather_kernel(
        const unsigned short* __restrict__ hp,
        const int* __restrict__ bcnt,
        const int* __restrict__ bpool,
        const float* __restrict__ bias,
        float* __restrict__ out,
        int n_nodes) {
    __shared__ int ecnt[NPG];
    __shared__ int eofs[NPG];
    __shared__ int epos[NPG];
    __shared__ int elist[ECAP];
    __shared__ int sflag;

    const int bkt = blockIdx.x >> 2;                   // bucket
    const int qr  = blockIdx.x & 3;                    // node quarter
    const int q0  = qr * NPG;                          // local node base
    const int nb0 = (bkt << NPBS) + q0;                // global node base
    const int tid = threadIdx.x;

    const int total = bcnt[bkt];
    const int count = min(total, CAP);
    const int* bp = bpool + (long)bkt * CAP;

    if (tid < NPG) ecnt[tid] = 0;
    if (tid == 0) sflag = 0;
    __syncthreads();

    // --- pass 1: degree histogram for our 32 nodes (native int LDS atomics)
    for (int i = tid; i < count; i += 256) {
        int nl = (bp[i] >> 20) - q0;
        if ((unsigned)nl < NPG) atomicAdd(&ecnt[nl], 1);
    }
    __syncthreads();

    // --- exclusive prefix scan of 32 degrees (lanes 0..31, shfl) ---
    if (tid < NPG) {
        int a = ecnt[tid];
        int s = a;
        #pragma unroll
        for (int d = 1; d < NPG; d <<= 1) {
            int t = __shfl_up(s, d);
            if (tid >= d) s += t;
        }
        eofs[tid] = s - a;
        epos[tid] = s - a;
    }
    __syncthreads();

    // --- pass 2: scatter src ids into per-node segments ---
    for (int i = tid; i < count; i += 256) {
        int e = bp[i];
        int nl = (e >> 20) - q0;
        if ((unsigned)nl < NPG) {
            int p = atomicAdd(&epos[nl], 1);           // ds_add_rtn_u32
            int s = e & 0xFFFFF;
            if (p < ECAP) {
                elist[p] = s;
            } else {                                   // cold spill path
                sflag = 1;
                float* o = out + ((long)((bkt << NPBS) + (e >> 20))) * F;
                const unsigned short* hr = hp + (long)s * F;
                for (int k = tid & 0; k < F; ++k)      // serial per edge (never runs)
                    unsafeAtomicAdd(o + k, bf16_to_f32(hr[k]));
            }
        }
    }
    __syncthreads();

    // --- accumulate in registers, fused bias+relu epilogue ---
    const int lane = tid & 63;
    const int w = tid >> 6;
    const bool ovf = (total > CAP) || (sflag != 0);
    const float2 bv = *(const float2*)(bias + (lane << 1));

    for (int nl = w; nl < NPG; nl += 4) {
        int n = nb0 + nl;
        if (n >= n_nodes) break;
        const int beg = eofs[nl];
        const int dend = min(beg + ecnt[nl], ECAP);

        float ax = 0.f, ay = 0.f;
        for (int i = beg; i < dend; i += 8) {          // 8 loads in flight
            unsigned v[8]; bool val[8];
            #pragma unroll
            for (int j = 0; j < 8; ++j) {
                val[j] = (i + j) < dend;
                int sid = elist[val[j] ? i + j : beg]; // uniform -> ds bcast
                v[j] = *(const unsigned*)(hp + ((long)sid << NPBS) + (lane << 1));
            }
            #pragma unroll
            for (int j = 0; j < 8; ++j) {
                if (val[j]) {
                    ax += __uint_as_float(v[j] << 16);
                    ay += __uint_as_float(v[j] & 0xffff0000u);
                }
            }
        }

        float* o = out + ((long)n << NPBS) + (lane << 1);
        if (ovf) {                                     // coherent read of spills
            ax += unsafeAtomicAdd(o, 0.f);
            ay += unsafeAtomicAdd(o + 1, 0.f);
        }
        float rx = fmaxf(ax + bv.x, 0.f);
        float ry = fmaxf(ay + bv.y, 0.f);
        *(float2*)o = make_float2(rx, ry);
    }
}

// ---------------------------------------------------------------------------
// Fallback tier (tiny ws or huge node ids): direct atomic scatter + fp32 GEMM.
// ---------------------------------------------------------------------------
__global__ void scatter_add_kernel(const float* __restrict__ h,
                                   const int* __restrict__ src,
                                   const int* __restrict__ dst,
                                   float* __restrict__ agg,
                                   long total) {
    long stride = (long)gridDim.x * blockDim.x;
    for (long i = (long)blockIdx.x * blockDim.x + threadIdx.x; i < total; i += stride) {
        int e    = (int)(i >> 5);
        int lane = (int)(i & 31);
        int s = src[e];
        int d = dst[e];
        float4 v = *(const float4*)(h + (long)s * F + (lane << 2));
        float* o = agg + (long)d * F + (lane << 2);
        unsafeAtomicAdd(o + 0, v.x);
        unsafeAtomicAdd(o + 1, v.y);
        unsafeAtomicAdd(o + 2, v.z);
        unsafeAtomicAdd(o + 3, v.w);
    }
}

__global__ __launch_bounds__(256) void gemm_bias_relu_inplace(
        float* __restrict__ out,
        const float* __restrict__ W,
        const float* __restrict__ bias,
        int n_rows) {
    __shared__ __align__(16) float a_t[KC][BR + 4];
    __shared__ __align__(16) float w_t[KC][F + 4];
    const int tid = threadIdx.x;
    const int tx = tid & 15;
    const int ty = tid >> 4;
    const int row0 = blockIdx.x * BR;
    float acc[4][8];
    #pragma unroll
    for (int i = 0; i < 4; ++i)
        #pragma unroll
        for (int j = 0; j < 8; ++j) acc[i][j] = 0.f;
    for (int kc = 0; kc < F; kc += KC) {
        #pragma unroll
        for (int p = 0; p < 2; ++p) {
            int q = tid + p * 256, r = q >> 3, kq = q & 7;
            int row = row0 + r;
            float4 v = make_float4(0.f, 0.f, 0.f, 0.f);
            if (row < n_rows) v = *(const float4*)(out + (long)row * F + kc + (kq << 2));
            a_t[kq * 4 + 0][r] = v.x; a_t[kq * 4 + 1][r] = v.y;
            a_t[kq * 4 + 2][r] = v.z; a_t[kq * 4 + 3][r] = v.w;
        }
        #pragma unroll
        for (int p = 0; p < 4; ++p) {
            int q = tid + p * 256, j = q >> 3, kq = q & 7;
            float4 v = *(const float4*)(W + (long)j * F + kc + (kq << 2));
            w_t[kq * 4 + 0][j] = v.x; w_t[kq * 4 + 1][j] = v.y;
            w_t[kq * 4 + 2][j] = v.z; w_t[kq * 4 + 3][j] = v.w;
        }
        __syncthreads();
        #pragma unroll
        for (int k = 0; k < KC; ++k) {
            float4 av = *(const float4*)&a_t[k][ty << 2];
            float4 w0 = *(const float4*)&w_t[k][tx << 2];
            float4 w1 = *(const float4*)&w_t[k][64 + (tx << 2)];
            float a4[4] = {av.x, av.y, av.z, av.w};
            float wv[8] = {w0.x, w0.y, w0.z, w0.w, w1.x, w1.y, w1.z, w1.w};
            #pragma unroll
            for (int i = 0; i < 4; ++i)
                #pragma unroll
                for (int j = 0; j < 8; ++j) acc[i][j] += a4[i] * wv[j];
        }
        __syncthreads();
    }
    float4 b0 = *(const float4*)(bias + (tx << 2));
    float4 b1 = *(const float4*)(bias + 64 + (tx << 2));
    #pragma unroll
    for (int i = 0; i < 4; ++i) {
        int row = row0 + (ty << 2) + i;
        if (row < n_rows) {
            float4 r0, r1;
            r0.x = fmaxf(acc[i][0] + b0.x, 0.f); r0.y = fmaxf(acc[i][1] + b0.y, 0.f);
            r0.z = fmaxf(acc[i][2] + b0.z, 0.f); r0.w = fmaxf(acc[i][3] + b0.w, 0.f);
            r1.x = fmaxf(acc[i][4] + b1.x, 0.f); r1.y = fmaxf(acc[i][5] + b1.y, 0.f);
            r1.z = fmaxf(acc[i][6] + b1.z, 0.f); r1.w = fmaxf(acc[i][7] + b1.w, 0.f);
            *(float4*)(out + (long)row * F + (tx << 2)) = r0;
            *(float4*)(out + (long)row * F + 64 + (tx << 2)) = r1;
        }
    }
}

extern "C" void kernel_launch(void* const* d_in, const int* in_sizes, int n_in,
                              void* d_out, int out_size, void* d_ws, size_t ws_size,
                              hipStream_t stream) {
    const float* h   = (const float*)d_in[0];
    const int*   src = (const int*)d_in[1];
    const int*   dst = (const int*)d_in[2];
    const float* W   = (const float*)d_in[3];
    const float* b   = (const float*)d_in[4];
    float* out = (float*)d_out;

    const int n_nodes = in_sizes[0] / F;
    const int n_edges = in_sizes[1];
    const int NB = (n_nodes + NPB - 1) >> NPBS;

    // ws layout: bcnt | bpool | hp (bf16 h@W^T) | Wb
    const size_t off_bcnt  = 0;
    const size_t off_bpool = 4096;
    const size_t off_hp    = off_bpool + (size_t)NB * CAP * sizeof(int);
    const size_t off_wb    = off_hp + (size_t)n_nodes * F * sizeof(unsigned short);
    const size_t need      = off_wb + (size_t)F * F * sizeof(unsigned short);

    if (ws_size >= need && n_nodes < (1 << 20) && NB <= NBMAX) {
        int* bcnt  = (int*)((char*)d_ws + off_bcnt);
        int* bpool = (int*)((char*)d_ws + off_bpool);
        unsigned short* hp = (unsigned short*)((char*)d_ws + off_hp);
        unsigned short* Wb = (unsigned short*)((char*)d_ws + off_wb);

        hipMemsetAsync(bcnt, 0, (size_t)NB * sizeof(int), stream);
        hipMemsetAsync(out, 0, (size_t)out_size * sizeof(float), stream);  // spill paths only

        conv_w_kernel<<<(F * F / 4 + 255) / 256, 256, 0, stream>>>(W, Wb, F * F / 4);

        const int ggrid = (n_nodes + 63) / 64;          // 4 waves x 16 rows
        gemm_h_kernel<<<ggrid, 256, 0, stream>>>(h, Wb, hp, n_nodes);

        build_buckets_kernel<<<512, 256, 0, stream>>>(
            src, dst, hp, bcnt, bpool, out, n_edges, NB);

        bucket_gather_kernel<<<NB * SPLIT, 256, 0, stream>>>(
            hp, bcnt, bpool, b, out, n_nodes);
    } else {
        hipMemsetAsync(out, 0, (size_t)out_size * sizeof(float), stream);
        scatter_add_kernel<<<16384, 256, 0, stream>>>(
            h, src, dst, out, (long)n_edges * 32);
        const int gblocks = (n_nodes + BR - 1) / BR;
        gemm_bias_relu_inplace<<<gblocks, 256, 0, stream>>>(out, W, b, n_nodes);
    }
}